// Round 10
// baseline (205.144 us; speedup 1.0000x reference)
//
#include <hip/hip_runtime.h>

#define HH 512
#define WW 512
#define NPLANE 48
#define BY 128
#define CHK 16
#define NCH (BY / CHK)   // 8 chunks per block
#define SLOTS 40         // ring slots per col (16B-aligned groups)
#define KS 11

typedef __attribute__((ext_vector_type(8))) short short8;   // 8 bf16 (A/B frag)
typedef __attribute__((ext_vector_type(4))) float floatx4;  // 4 fp32 (C/D frag)
typedef __attribute__((ext_vector_type(2))) float float2v;
typedef __attribute__((ext_vector_type(2))) __bf16 bf16x2v;

// exact RNE pack (weights, once)
__device__ inline unsigned pk2bf_rne(float a, float b) {
    union { float f; unsigned u; } ua, ub;
    ua.f = a; ub.f = b;
    unsigned lo = (ua.u + 0x7FFFu + ((ua.u >> 16) & 1u)) >> 16;
    unsigned hi = (ub.u + 0x7FFFu + ((ub.u >> 16) & 1u)) >> 16;
    return lo | (hi << 16);
}

// hot-path pack: float2 -> bf16x2; lowers to v_cvt_pk_bf16_f32 on gfx950
__device__ inline unsigned pkbf(float a, float b) {
    float2v f = {a, b};
    bf16x2v v = __builtin_convertvector(f, bf16x2v);
    return __builtin_bit_cast(unsigned, v);
}

struct Raw { float4 p0, p1, t0, t1; };

// Fully-MFMA SSIM: h-blur = data x W (banded), v-blur = W x ring.
// Wave-private LDS ring strips -> no barriers. 4-deep register prefetch of
// raw chunks (~1600 cyc load-to-use > 900 cyc HBM miss latency) + hoisted
// v-fragment ds_reads (in-order same-wave DS makes the WAR slot reuse safe).
__global__ __launch_bounds__(256, 4) void ssim_kernel(
    const float* __restrict__ pred, const float* __restrict__ target,
    float* __restrict__ ws_sum)
{
    // ring[wave][ch][col][slot], bf16: 4*5*16*40*2 = 25600 B
    __shared__ __align__(16) short ring[4][5][16][SLOTS];
    __shared__ float red[4];

    const int tid = threadIdx.x;
    const int wv = tid >> 6;
    const int lane = tid & 63;
    const int m = lane & 15;     // A-row / B-col / C-col index
    const int quad = lane >> 4;  // k-group / C-row-group

    // Gaussian weights, sigma=1.5
    float wsum = 0.f;
#pragma unroll
    for (int k = 0; k < KS; ++k) {
        float d = (float)(k - 5);
        wsum += __expf(-d * d * (1.0f / 4.5f));
    }
    const float invs = 1.0f / wsum;

    // Banded weight fragment: value at k=quad*8+j is w[k - m - 3] (0 outside band).
    // Serves as B in h-mfma (B[k][n]=w[k-n-3]) and A in v-mfma (A[m][k]=w[k-m-3]).
    short8 Wf;
    {
        union { short8 v; unsigned u[4]; } W;
#pragma unroll
        for (int jj = 0; jj < 4; ++jj) {
            float v0, v1;
            {
                int idx = quad * 8 + 2 * jj - m - 3;
                float d = (float)(idx - 5);
                v0 = (idx >= 0 && idx < KS) ? __expf(-d * d * (1.0f / 4.5f)) * invs : 0.f;
            }
            {
                int idx = quad * 8 + 2 * jj + 1 - m - 3;
                float d = (float)(idx - 5);
                v1 = (idx >= 0 && idx < KS) ? __expf(-d * d * (1.0f / 4.5f)) * invs : 0.f;
            }
            W.u[jj] = pk2bf_rne(v0, v1);
        }
        Wf = W.v;
    }

    const size_t poff = (size_t)blockIdx.z * HH * WW;
    const float* __restrict__ pp = pred + poff;
    const float* __restrict__ tp = target + poff;
    const int X0 = blockIdx.x * 64 + wv * 16;  // wave's 16-col tile
    const int rawX = X0 - 8;                   // 32-col raw window base
    const int Y0 = blockIdx.y * BY;

    const float C1 = 1.0e-4f;
    const float C2 = 9.0e-4f;
    float lsum = 0.f;
    const floatx4 z = {0.f, 0.f, 0.f, 0.f};

    // load chunk k's raw rows (zero-padded outside the image)
    auto load_raw = [&](int k) -> Raw {
        Raw r;
        r.p0 = make_float4(0, 0, 0, 0); r.p1 = make_float4(0, 0, 0, 0);
        r.t0 = make_float4(0, 0, 0, 0); r.t1 = make_float4(0, 0, 0, 0);
        const int row = Y0 + CHK * k - 8 + m;
        if ((unsigned)row < (unsigned)HH) {
            const float* pr = pp + (size_t)row * WW;
            const float* tr = tp + (size_t)row * WW;
            const int c0 = rawX + quad * 8;
            if ((unsigned)c0 < (unsigned)WW) {
                r.p0 = *(const float4*)(pr + c0);
                r.t0 = *(const float4*)(tr + c0);
            }
            if ((unsigned)(c0 + 4) < (unsigned)WW) {
                r.p1 = *(const float4*)(pr + c0 + 4);
                r.t1 = *(const float4*)(tr + c0 + 4);
            }
        }
        return r;
    };

    // h-step: pack raw -> bf16 frags, 5 MFMA, pack D -> ring at slot base sb
    auto h_step = [&](const Raw& r, int sb) {
        const float p[8] = {r.p0.x, r.p0.y, r.p0.z, r.p0.w,
                            r.p1.x, r.p1.y, r.p1.z, r.p1.w};
        const float t[8] = {r.t0.x, r.t0.y, r.t0.z, r.t0.w,
                            r.t1.x, r.t1.y, r.t1.z, r.t1.w};
        union { short8 v; unsigned u[4]; } Fp, Ft, Fpp, Ftt, Fpt;
#pragma unroll
        for (int jj = 0; jj < 4; ++jj) {
            const float a0 = p[2 * jj], a1 = p[2 * jj + 1];
            const float b0 = t[2 * jj], b1 = t[2 * jj + 1];
            Fp.u[jj]  = pkbf(a0, a1);
            Ft.u[jj]  = pkbf(b0, b1);
            Fpp.u[jj] = pkbf(a0 * a0, a1 * a1);
            Ftt.u[jj] = pkbf(b0 * b0, b1 * b1);
            Fpt.u[jj] = pkbf(a0 * b0, a1 * b1);
        }
        floatx4 Dp  = __builtin_amdgcn_mfma_f32_16x16x32_bf16(Fp.v,  Wf, z, 0, 0, 0);
        floatx4 Dt  = __builtin_amdgcn_mfma_f32_16x16x32_bf16(Ft.v,  Wf, z, 0, 0, 0);
        floatx4 Dpp = __builtin_amdgcn_mfma_f32_16x16x32_bf16(Fpp.v, Wf, z, 0, 0, 0);
        floatx4 Dtt = __builtin_amdgcn_mfma_f32_16x16x32_bf16(Ftt.v, Wf, z, 0, 0, 0);
        floatx4 Dpt = __builtin_amdgcn_mfma_f32_16x16x32_bf16(Fpt.v, Wf, z, 0, 0, 0);
        // C-layout: col = lane&15 (=m), rows = quad*4 + reg -> slots sb+quad*4+reg
        int slot = sb + quad * 4;
        if (slot >= SLOTS) slot -= SLOTS;
        uint2 v;
        v.x = pkbf(Dp[0], Dp[1]);   v.y = pkbf(Dp[2], Dp[3]);
        *(uint2*)&ring[wv][0][m][slot] = v;
        v.x = pkbf(Dt[0], Dt[1]);   v.y = pkbf(Dt[2], Dt[3]);
        *(uint2*)&ring[wv][1][m][slot] = v;
        v.x = pkbf(Dpp[0], Dpp[1]); v.y = pkbf(Dpp[2], Dpp[3]);
        *(uint2*)&ring[wv][2][m][slot] = v;
        v.x = pkbf(Dtt[0], Dtt[1]); v.y = pkbf(Dtt[2], Dtt[3]);
        *(uint2*)&ring[wv][3][m][slot] = v;
        v.x = pkbf(Dpt[0], Dpt[1]); v.y = pkbf(Dpt[2], Dpt[3]);
        *(uint2*)&ring[wv][4][m][slot] = v;
    };

    // one pipeline body: vread(i) -> h(i+2, buf) -> refill buf=load(i+6) -> v-SSIM(i)
    auto body = [&](int i, Raw& buf, int& hb, int& vb) {
        // hoisted v-fragment reads (rows 16i-8 .. 16i+23); issued before the
        // aliasing h-writes -> in-order DS returns pre-write data (wave-private)
        int sq = vb + quad * 8;
        if (sq >= SLOTS) sq -= SLOTS;
        const short8 Bp  = *(const short8*)&ring[wv][0][m][sq];
        const short8 Bt  = *(const short8*)&ring[wv][1][m][sq];
        const short8 Bpp = *(const short8*)&ring[wv][2][m][sq];
        const short8 Btt = *(const short8*)&ring[wv][3][m][sq];
        const short8 Bpt = *(const short8*)&ring[wv][4][m][sq];
        vb += CHK; if (vb >= SLOTS) vb -= SLOTS;

        if (i + 2 <= NCH) {
            h_step(buf, hb);
            hb += CHK; if (hb >= SLOTS) hb -= SLOTS;
        }
        if (i + 6 <= NCH) buf = load_raw(i + 6);   // 4-chunk-deep prefetch

        floatx4 Mp  = __builtin_amdgcn_mfma_f32_16x16x32_bf16(Wf, Bp,  z, 0, 0, 0);
        floatx4 Mt  = __builtin_amdgcn_mfma_f32_16x16x32_bf16(Wf, Bt,  z, 0, 0, 0);
        floatx4 Mpp = __builtin_amdgcn_mfma_f32_16x16x32_bf16(Wf, Bpp, z, 0, 0, 0);
        floatx4 Mtt = __builtin_amdgcn_mfma_f32_16x16x32_bf16(Wf, Btt, z, 0, 0, 0);
        floatx4 Mpt = __builtin_amdgcn_mfma_f32_16x16x32_bf16(Wf, Bpt, z, 0, 0, 0);
#pragma unroll
        for (int r = 0; r < 4; ++r) {
            const float mup = Mp[r], mut = Mt[r];
            const float mupsq = mup * mup, mutsq = mut * mut, mucr = mup * mut;
            const float sp2 = Mpp[r] - mupsq;
            const float st2 = Mtt[r] - mutsq;
            const float scr = Mpt[r] - mucr;
            const float n1 = 2.f * mucr + C1;
            const float n2 = 2.f * scr + C2;
            const float d1 = mupsq + mutsq + C1;
            const float d2 = sp2 + st2 + C2;
            lsum += __fdividef(n1 * n2, d1 * d2);
        }
    };

    // Prologue: fill the 4-deep pipe.  Buffer rotation (static, unroll-4):
    // chunk k is held in buffer (k & 3): A=0, B=1, C=2, D=3 after prologue reloads.
    Raw A = load_raw(0);
    Raw B = load_raw(1);
    Raw C = load_raw(2);
    Raw D = load_raw(3);
    int hb = (SLOTS - 8) % SLOTS;   // 32
    int vb = SLOTS - 8;             // 32
    h_step(A, hb); hb += CHK; if (hb >= SLOTS) hb -= SLOTS;
    A = load_raw(4);
    h_step(B, hb); hb += CHK; if (hb >= SLOTS) hb -= SLOTS;
    B = load_raw(5);

    // 8 chunks = 2 passes of 4 statically-rotated bodies
#pragma unroll 1
    for (int jo = 0; jo < NCH; jo += 4) {
        body(jo + 0, C, hb, vb);   // h(jo+2) uses C (=load(jo+2)), refills load(jo+6)
        body(jo + 1, D, hb, vb);
        body(jo + 2, A, hb, vb);
        body(jo + 3, B, hb, vb);
    }

    // wave reduce -> block reduce -> one atomic per block
#pragma unroll
    for (int off = 32; off > 0; off >>= 1) lsum += __shfl_down(lsum, off, 64);
    if (lane == 0) red[wv] = lsum;
    __syncthreads();
    if (tid == 0) {
        atomicAdd(ws_sum, red[0] + red[1] + red[2] + red[3]);
    }
}

__global__ void finalize_kernel(const float* __restrict__ ws_sum,
                                float* __restrict__ out) {
    out[0] = 1.0f - ws_sum[0] * (1.0f / 12582912.0f);  // N = 16*3*512*512
}

extern "C" void kernel_launch(void* const* d_in, const int* in_sizes, int n_in,
                              void* d_out, int out_size, void* d_ws, size_t ws_size,
                              hipStream_t stream) {
    const float* pred = (const float*)d_in[0];
    const float* target = (const float*)d_in[1];
    float* out = (float*)d_out;
    float* ws = (float*)d_ws;

    hipMemsetAsync(ws, 0, sizeof(float), stream);       // graph-capturable
    dim3 grid(WW / 64, HH / BY, NPLANE);                // 8 x 4 x 48 = 1536 blocks
    ssim_kernel<<<grid, 256, 0, stream>>>(pred, target, ws);
    finalize_kernel<<<1, 1, 0, stream>>>(ws, out);
}

// Round 11
// 142.120 us; speedup vs baseline: 1.4435x; 1.4435x over previous
//
#include <hip/hip_runtime.h>

#define HH 512
#define WW 512
#define NPLANE 48
#define BY 256
#define CHK 16
#define NCH (BY / CHK)   // 16 chunks per block
#define SLOTS 40         // ring slots per col (16B-aligned groups)
#define KS 11

typedef __attribute__((ext_vector_type(8))) short short8;   // 8 bf16 (A/B frag)
typedef __attribute__((ext_vector_type(4))) float floatx4;  // 4 fp32 (C/D frag)
typedef __attribute__((ext_vector_type(2))) float float2v;
typedef __attribute__((ext_vector_type(2))) __bf16 bf16x2v;

// exact RNE pack (weights, once)
__device__ inline unsigned pk2bf_rne(float a, float b) {
    union { float f; unsigned u; } ua, ub;
    ua.f = a; ub.f = b;
    unsigned lo = (ua.u + 0x7FFFu + ((ua.u >> 16) & 1u)) >> 16;
    unsigned hi = (ub.u + 0x7FFFu + ((ub.u >> 16) & 1u)) >> 16;
    return lo | (hi << 16);
}

// hot-path pack: float2 -> bf16x2; lowers to v_cvt_pk_bf16_f32 on gfx950
__device__ inline unsigned pkbf(float a, float b) {
    float2v f = {a, b};
    bf16x2v v = __builtin_convertvector(f, bf16x2v);
    return __builtin_bit_cast(unsigned, v);
}

struct Raw { float4 p0, p1, t0, t1; };

// Fully-MFMA SSIM: h-blur = data x W (banded), v-blur = W x ring.
// Wave-private LDS ring strips -> no barriers in the loop.
// BY=256 -> 768 blocks = exactly 3 resident blocks/CU, one uniform dispatch
// round (R10's 1536 blocks gave a half-empty 0.5-round tail).
// Depth-2 prefetch uses plain named locals A/B (R10's Raw& lambda param
// made them address-taken -> 151 MB of scratch spill).
__global__ __launch_bounds__(256, 3) void ssim_kernel(
    const float* __restrict__ pred, const float* __restrict__ target,
    float* __restrict__ ws_sum)
{
    // ring[wave][ch][col][slot], bf16: 4*5*16*40*2 = 25600 B
    __shared__ __align__(16) short ring[4][5][16][SLOTS];
    __shared__ float red[4];

    const int tid = threadIdx.x;
    const int wv = tid >> 6;
    const int lane = tid & 63;
    const int m = lane & 15;     // A-row / B-col / C-col index
    const int quad = lane >> 4;  // k-group / C-row-group

    // Gaussian weights, sigma=1.5
    float wsum = 0.f;
#pragma unroll
    for (int k = 0; k < KS; ++k) {
        float d = (float)(k - 5);
        wsum += __expf(-d * d * (1.0f / 4.5f));
    }
    const float invs = 1.0f / wsum;

    // Banded weight fragment: value at k=quad*8+j is w[k - m - 3] (0 outside band).
    // Serves as B in h-mfma (B[k][n]=w[k-n-3]) and A in v-mfma (A[m][k]=w[k-m-3]).
    short8 Wf;
    {
        union { short8 v; unsigned u[4]; } W;
#pragma unroll
        for (int jj = 0; jj < 4; ++jj) {
            float v0, v1;
            {
                int idx = quad * 8 + 2 * jj - m - 3;
                float d = (float)(idx - 5);
                v0 = (idx >= 0 && idx < KS) ? __expf(-d * d * (1.0f / 4.5f)) * invs : 0.f;
            }
            {
                int idx = quad * 8 + 2 * jj + 1 - m - 3;
                float d = (float)(idx - 5);
                v1 = (idx >= 0 && idx < KS) ? __expf(-d * d * (1.0f / 4.5f)) * invs : 0.f;
            }
            W.u[jj] = pk2bf_rne(v0, v1);
        }
        Wf = W.v;
    }

    const size_t poff = (size_t)blockIdx.z * HH * WW;
    const float* __restrict__ pp = pred + poff;
    const float* __restrict__ tp = target + poff;
    const int X0 = blockIdx.x * 64 + wv * 16;  // wave's 16-col tile
    const int rawX = X0 - 8;                   // 32-col raw window base
    const int Y0 = blockIdx.y * BY;

    const float C1 = 1.0e-4f;
    const float C2 = 9.0e-4f;
    float lsum = 0.f;
    const floatx4 z = {0.f, 0.f, 0.f, 0.f};

    // load chunk k's raw rows (zero-padded outside the image)
    auto load_raw = [&](int k) -> Raw {
        Raw r;
        r.p0 = make_float4(0, 0, 0, 0); r.p1 = make_float4(0, 0, 0, 0);
        r.t0 = make_float4(0, 0, 0, 0); r.t1 = make_float4(0, 0, 0, 0);
        const int row = Y0 + CHK * k - 8 + m;
        if ((unsigned)row < (unsigned)HH) {
            const float* pr = pp + (size_t)row * WW;
            const float* tr = tp + (size_t)row * WW;
            const int c0 = rawX + quad * 8;
            if ((unsigned)c0 < (unsigned)WW) {
                r.p0 = *(const float4*)(pr + c0);
                r.t0 = *(const float4*)(tr + c0);
            }
            if ((unsigned)(c0 + 4) < (unsigned)WW) {
                r.p1 = *(const float4*)(pr + c0 + 4);
                r.t1 = *(const float4*)(tr + c0 + 4);
            }
        }
        return r;
    };

    // h-step: pack raw -> bf16 frags, 5 MFMA, pack D -> ring at slot base sb
    auto h_step = [&](const Raw& r, int sb) {
        const float p[8] = {r.p0.x, r.p0.y, r.p0.z, r.p0.w,
                            r.p1.x, r.p1.y, r.p1.z, r.p1.w};
        const float t[8] = {r.t0.x, r.t0.y, r.t0.z, r.t0.w,
                            r.t1.x, r.t1.y, r.t1.z, r.t1.w};
        union { short8 v; unsigned u[4]; } Fp, Ft, Fpp, Ftt, Fpt;
#pragma unroll
        for (int jj = 0; jj < 4; ++jj) {
            const float a0 = p[2 * jj], a1 = p[2 * jj + 1];
            const float b0 = t[2 * jj], b1 = t[2 * jj + 1];
            Fp.u[jj]  = pkbf(a0, a1);
            Ft.u[jj]  = pkbf(b0, b1);
            Fpp.u[jj] = pkbf(a0 * a0, a1 * a1);
            Ftt.u[jj] = pkbf(b0 * b0, b1 * b1);
            Fpt.u[jj] = pkbf(a0 * b0, a1 * b1);
        }
        floatx4 Dp  = __builtin_amdgcn_mfma_f32_16x16x32_bf16(Fp.v,  Wf, z, 0, 0, 0);
        floatx4 Dt  = __builtin_amdgcn_mfma_f32_16x16x32_bf16(Ft.v,  Wf, z, 0, 0, 0);
        floatx4 Dpp = __builtin_amdgcn_mfma_f32_16x16x32_bf16(Fpp.v, Wf, z, 0, 0, 0);
        floatx4 Dtt = __builtin_amdgcn_mfma_f32_16x16x32_bf16(Ftt.v, Wf, z, 0, 0, 0);
        floatx4 Dpt = __builtin_amdgcn_mfma_f32_16x16x32_bf16(Fpt.v, Wf, z, 0, 0, 0);
        // C-layout: col = lane&15 (=m), rows = quad*4 + reg -> slots sb+quad*4+reg
        int slot = sb + quad * 4;
        if (slot >= SLOTS) slot -= SLOTS;
        uint2 v;
        v.x = pkbf(Dp[0], Dp[1]);   v.y = pkbf(Dp[2], Dp[3]);
        *(uint2*)&ring[wv][0][m][slot] = v;
        v.x = pkbf(Dt[0], Dt[1]);   v.y = pkbf(Dt[2], Dt[3]);
        *(uint2*)&ring[wv][1][m][slot] = v;
        v.x = pkbf(Dpp[0], Dpp[1]); v.y = pkbf(Dpp[2], Dpp[3]);
        *(uint2*)&ring[wv][2][m][slot] = v;
        v.x = pkbf(Dtt[0], Dtt[1]); v.y = pkbf(Dtt[2], Dtt[3]);
        *(uint2*)&ring[wv][3][m][slot] = v;
        v.x = pkbf(Dpt[0], Dpt[1]); v.y = pkbf(Dpt[2], Dpt[3]);
        *(uint2*)&ring[wv][4][m][slot] = v;
    };

    // v-tail shared by both unrolled bodies: MFMA + SSIM accumulate
    auto v_tail = [&](short8 Bp, short8 Bt, short8 Bpp, short8 Btt, short8 Bpt) {
        floatx4 Mp  = __builtin_amdgcn_mfma_f32_16x16x32_bf16(Wf, Bp,  z, 0, 0, 0);
        floatx4 Mt  = __builtin_amdgcn_mfma_f32_16x16x32_bf16(Wf, Bt,  z, 0, 0, 0);
        floatx4 Mpp = __builtin_amdgcn_mfma_f32_16x16x32_bf16(Wf, Bpp, z, 0, 0, 0);
        floatx4 Mtt = __builtin_amdgcn_mfma_f32_16x16x32_bf16(Wf, Btt, z, 0, 0, 0);
        floatx4 Mpt = __builtin_amdgcn_mfma_f32_16x16x32_bf16(Wf, Bpt, z, 0, 0, 0);
#pragma unroll
        for (int r = 0; r < 4; ++r) {
            const float mup = Mp[r], mut = Mt[r];
            const float mupsq = mup * mup, mutsq = mut * mut, mucr = mup * mut;
            const float sp2 = Mpp[r] - mupsq;
            const float st2 = Mtt[r] - mutsq;
            const float scr = Mpt[r] - mucr;
            const float n1 = 2.f * mucr + C1;
            const float n2 = 2.f * scr + C2;
            const float d1 = mupsq + mutsq + C1;
            const float d2 = sp2 + st2 + C2;
            lsum += __fdividef(n1 * n2, d1 * d2);
        }
    };

    // Prologue: depth-2 pipe. A holds even chunks, B holds odd chunks.
    Raw A = load_raw(0);
    Raw B = load_raw(1);
    int hb = SLOTS - 8;   // 32
    int vb = SLOTS - 8;   // 32
    h_step(A, hb); hb += CHK; if (hb >= SLOTS) hb -= SLOTS;
    A = load_raw(2);
    h_step(B, hb); hb += CHK; if (hb >= SLOTS) hb -= SLOTS;
    B = load_raw(3);

#pragma unroll 1
    for (int i = 0; i < NCH; i += 2) {
        // ---- body: chunk i (uses A for h(i+2)) ----
        {
            int sq = vb + quad * 8;
            if (sq >= SLOTS) sq -= SLOTS;
            const short8 Bp  = *(const short8*)&ring[wv][0][m][sq];
            const short8 Bt  = *(const short8*)&ring[wv][1][m][sq];
            const short8 Bpp = *(const short8*)&ring[wv][2][m][sq];
            const short8 Btt = *(const short8*)&ring[wv][3][m][sq];
            const short8 Bpt = *(const short8*)&ring[wv][4][m][sq];
            vb += CHK; if (vb >= SLOTS) vb -= SLOTS;
            if (i + 2 <= NCH) {
                h_step(A, hb);
                hb += CHK; if (hb >= SLOTS) hb -= SLOTS;
            }
            if (i + 4 <= NCH) A = load_raw(i + 4);
            v_tail(Bp, Bt, Bpp, Btt, Bpt);
        }
        // ---- body: chunk i+1 (uses B for h(i+3)) ----
        {
            int sq = vb + quad * 8;
            if (sq >= SLOTS) sq -= SLOTS;
            const short8 Bp  = *(const short8*)&ring[wv][0][m][sq];
            const short8 Bt  = *(const short8*)&ring[wv][1][m][sq];
            const short8 Bpp = *(const short8*)&ring[wv][2][m][sq];
            const short8 Btt = *(const short8*)&ring[wv][3][m][sq];
            const short8 Bpt = *(const short8*)&ring[wv][4][m][sq];
            vb += CHK; if (vb >= SLOTS) vb -= SLOTS;
            if (i + 3 <= NCH) {
                h_step(B, hb);
                hb += CHK; if (hb >= SLOTS) hb -= SLOTS;
            }
            if (i + 5 <= NCH) B = load_raw(i + 5);
            v_tail(Bp, Bt, Bpp, Btt, Bpt);
        }
    }

    // wave reduce -> block reduce -> one atomic per block
#pragma unroll
    for (int off = 32; off > 0; off >>= 1) lsum += __shfl_down(lsum, off, 64);
    if (lane == 0) red[wv] = lsum;
    __syncthreads();
    if (tid == 0) {
        atomicAdd(ws_sum, red[0] + red[1] + red[2] + red[3]);
    }
}

__global__ void finalize_kernel(const float* __restrict__ ws_sum,
                                float* __restrict__ out) {
    out[0] = 1.0f - ws_sum[0] * (1.0f / 12582912.0f);  // N = 16*3*512*512
}

extern "C" void kernel_launch(void* const* d_in, const int* in_sizes, int n_in,
                              void* d_out, int out_size, void* d_ws, size_t ws_size,
                              hipStream_t stream) {
    const float* pred = (const float*)d_in[0];
    const float* target = (const float*)d_in[1];
    float* out = (float*)d_out;
    float* ws = (float*)d_ws;

    hipMemsetAsync(ws, 0, sizeof(float), stream);       // graph-capturable
    dim3 grid(WW / 64, HH / BY, NPLANE);                // 8 x 2 x 48 = 768 blocks
    ssim_kernel<<<grid, 256, 0, stream>>>(pred, target, ws);
    finalize_kernel<<<1, 1, 0, stream>>>(ws, out);
}